// Round 8
// baseline (860.278 us; speedup 1.0000x reference)
//
#include <hip/hip_runtime.h>

// Windowed attention block (B=32, C=128->256->128, H=W=112, WS=7, T=256 windows).
// fp32 I/O, bf16 MFMA internal.
// Window-ordered pixel index: wpx = j*49 + pq  (j = h1*16+w1, pq = p*7+q).
// ws (616.6MB): QW [32][12544 wpx][128] bf16 | KW same | VW [32][12544*? ] = [b][wpx*256+d] bf16
//               GN [32][12544 px][256 d] bf16 (spatial px) | params f32
// aliases: P bf16 [32][256][256] -> QW base (after k_dots reads QW)
//          Pp f32 [8][32][256][256] -> GN base (live k_dots..k_smax)
//          wfused bf16 [512][128] -> GN base (live k_wconv..k_qkv)
//          XN bf16 [32][12544 wpx][128] -> GN base + 2MB (live k_xpose..k_qkv)

typedef unsigned short u16;
typedef unsigned int u32;
typedef short s16x8 __attribute__((ext_vector_type(8)));
typedef float f32x4 __attribute__((ext_vector_type(4)));
typedef u16 u16x8 __attribute__((ext_vector_type(8)));
typedef u16 u16x4 __attribute__((ext_vector_type(4)));

#define EPSV 1e-5f

__device__ __forceinline__ float bf2f(u16 h) {
  u32 u = ((u32)h) << 16;
  return __builtin_bit_cast(float, u);
}
__device__ __forceinline__ u16 f2bf(float f) {
  u32 u = __builtin_bit_cast(u32, f);
  u += 0x7FFFu + ((u >> 16) & 1u);
  return (u16)(u >> 16);
}
__device__ __forceinline__ s16x8 ld8(const u16* p) { return *(const s16x8*)p; }
__device__ __forceinline__ f32x4 mfma_bf16(s16x8 a, s16x8 b, f32x4 c) {
  return __builtin_amdgcn_mfma_f32_16x16x32_bf16(a, b, c, 0, 0, 0);
}
__device__ __forceinline__ float gelu_f(float v) {
  float e = exp2f(-2.3022083f * (v + 0.044715f * v * v * v));
  return v / (1.0f + e);
}

// ---------------- K0: fold BN params ----------------
__global__ void k_params(
    const float* __restrict__ gq, const float* __restrict__ bq, const float* __restrict__ mq, const float* __restrict__ vq,
    const float* __restrict__ gk, const float* __restrict__ bk, const float* __restrict__ mk, const float* __restrict__ vk,
    const float* __restrict__ gv, const float* __restrict__ bv, const float* __restrict__ mv, const float* __restrict__ vv,
    const float* __restrict__ bo, const float* __restrict__ go, const float* __restrict__ bbo, const float* __restrict__ mo,
    const float* __restrict__ vo,
    float* __restrict__ sc512, float* __restrict__ sh512, float* __restrict__ sco, float* __restrict__ sho)
{
  const int i = threadIdx.x;
  if (i < 128) {
    const float s = gq[i] * rsqrtf(vq[i] + EPSV);
    sc512[i] = s;
    sh512[i] = bq[i] - mq[i] * s;
    const float so = go[i] * rsqrtf(vo[i] + EPSV);
    sco[i] = so;
    sho[i] = (bo[i] - mo[i]) * so + bbo[i];
  } else if (i < 256) {
    const int c = i - 128;
    const float s = gk[c] * rsqrtf(vk[c] + EPSV);
    sc512[i] = s;
    sh512[i] = bk[c] - mk[c] * s;
  } else if (i < 512) {
    const int c = i - 256;
    const float s = gv[c] * rsqrtf(vv[c] + EPSV);
    sc512[i] = s;
    sh512[i] = bv[c] - mv[c] * s;
  }
}

// ---------------- K0b: convert+scale-fold QKV weights to bf16 ----------------
__global__ void k_wconv(const float* __restrict__ wq, const float* __restrict__ wk,
                        const float* __restrict__ wv, const float* __restrict__ sc512,
                        u16* __restrict__ wfused)
{
  const int idx4 = (blockIdx.x * 256 + threadIdx.x) * 4;  // 0..65532
  const int co = idx4 >> 7, c = idx4 & 127;
  const float* src = (co < 128) ? (wq + co * 128 + c)
                   : (co < 256) ? (wk + (co - 128) * 128 + c)
                                : (wv + (co - 256) * 128 + c);
  const float s = sc512[co];
  const float4 v = *(const float4*)src;
  u16x4 r;
  r[0] = f2bf(v.x * s); r[1] = f2bf(v.y * s);
  r[2] = f2bf(v.z * s); r[3] = f2bf(v.w * s);
  *(u16x4*)(wfused + idx4) = r;
}

// ---------------- K0d: transpose x NCHW fp32 -> XN [b][wpx][c] bf16 (window-ordered) ----------------
// tile 256px x 128c, 512 thr. Register 4x4 transpose; vector LDS both sides.
// Reads contiguous; writes carry the window scatter (1792B runs).
__global__ __launch_bounds__(512, 2) void k_xpose(
    const float* __restrict__ x, u16* __restrict__ XN)
{
  __shared__ u16 XT[256 * 128];  // [px][c ^ swz(px)]
  const int b = blockIdx.y;
  const int px0 = blockIdx.x * 256;
  const int t = threadIdx.x;
  const int pg4 = t & 15, c0 = t >> 4;  // c0 0..31 (4-c groups), pg4: 4-px groups

  #pragma unroll
  for (int it = 0; it < 4; ++it) {
    const int pxb = it * 64 + pg4 * 4;
    float4 v[4];
    #pragma unroll
    for (int cc = 0; cc < 4; ++cc)
      v[cc] = *(const float4*)(x + ((size_t)b * 128 + c0 * 4 + cc) * 12544 + px0 + pxb);
    #pragma unroll
    for (int pp = 0; pp < 4; ++pp) {
      const int px = pxb + pp;
      u16x4 pk;
      pk[0] = f2bf(v[0][pp]); pk[1] = f2bf(v[1][pp]);
      pk[2] = f2bf(v[2][pp]); pk[3] = f2bf(v[3][pp]);
      *(u16x4*)&XT[px * 128 + ((c0 * 4) ^ (((px >> 2) & 15) << 3))] = pk;
    }
  }
  __syncthreads();
  // write out: thread t -> local px = t>>1, 64-channel half; dst row = window-ordered wpx
  const int pxl = t >> 1, half = (t & 1) * 64;
  const int swz = ((pxl >> 2) & 15) << 3;
  const int px = px0 + pxl;
  const int hh = px / 112, ww = px - hh * 112;
  const int h1 = hh / 7, p = hh - h1 * 7;
  const int w1 = ww / 7, q = ww - w1 * 7;
  const int wpx = (h1 * 16 + w1) * 49 + p * 7 + q;
  u16* dst = XN + ((size_t)b * 12544 + wpx) * 128 + half;
  #pragma unroll
  for (int i = 0; i < 8; ++i)
    *(u16x8*)(dst + i * 8) = *(const u16x8*)&XT[pxl * 128 + ((half + i * 8) ^ swz)];
}

// ---------------- K1: QKV projection (+folded BN) ----------------
// px-tile 128 (window-ordered), 256 thr, 32KB LDS -> 4 blocks/CU.
// A-frags direct from XN (contiguous); ALL outputs fully linear in wpx.
__global__ __launch_bounds__(256, 4) void k_qkv(
    const u16* __restrict__ XN, const u16* __restrict__ wfused,
    const float* __restrict__ sh512,
    u16* __restrict__ QW, u16* __restrict__ KW, u16* __restrict__ VW)
{
  __shared__ u16 XT[128 * 128];  // output tile [pxl][co ^ ((pxl&15)<<3)]
  const int b = blockIdx.y;
  const int px0 = blockIdx.x * 128;   // wpx base
  const int t = threadIdx.x;
  const int pxl = t & 127, chalf = (t >> 7) * 64;
  const int w = t >> 6, l = t & 63, a15 = l & 15, g = l >> 4;

  // A fragments direct from XN (block reads 32KB contiguous)
  s16x8 af[2][4];
  #pragma unroll
  for (int pxt = 0; pxt < 2; ++pxt) {
    const size_t rowb = ((size_t)b * 12544 + px0 + w * 32 + pxt * 16 + a15) * 128;
    #pragma unroll
    for (int ks = 0; ks < 4; ++ks)
      af[pxt][ks] = ld8(XN + rowb + ks * 32 + g * 8);
  }

  // linear output rows: wpx = px0 + pxl
  const size_t wpx = (size_t)px0 + pxl;
  u16* const qrow = QW + ((size_t)b * 12544 + wpx) * 128 + chalf;
  u16* const krow = KW + ((size_t)b * 12544 + wpx) * 128 + chalf;
  u16* const vrow = VW + (size_t)b * 3211264 + wpx * 256 + chalf;  // 12544 = 49*256
  const int swf = (pxl & 15) << 3;

  #pragma unroll 1
  for (int phase = 0; phase < 4; ++phase) {
    float shv[8];
    #pragma unroll
    for (int c8 = 0; c8 < 8; ++c8) shv[c8] = sh512[phase * 128 + c8 * 16 + a15];

    #pragma unroll
    for (int cot8 = 0; cot8 < 8; ++cot8) {
      s16x8 bfr[4];
      const u16* wrow = wfused + (u32)(phase * 128 + cot8 * 16 + a15) * 128u;
      #pragma unroll
      for (int ks = 0; ks < 4; ++ks) bfr[ks] = ld8(wrow + ks * 32 + g * 8);

      f32x4 acc[2];
      #pragma unroll
      for (int pxt = 0; pxt < 2; ++pxt) { acc[pxt][0]=0.f; acc[pxt][1]=0.f; acc[pxt][2]=0.f; acc[pxt][3]=0.f; }
      #pragma unroll
      for (int ks = 0; ks < 4; ++ks)
        #pragma unroll
        for (int pxt = 0; pxt < 2; ++pxt)
          acc[pxt] = mfma_bf16(af[pxt][ks], bfr[ks], acc[pxt]);

      const int co = cot8 * 16 + a15;
      #pragma unroll
      for (int pxt = 0; pxt < 2; ++pxt) {
        #pragma unroll
        for (int r = 0; r < 4; ++r) {
          const int prow = w * 32 + pxt * 16 + g * 4 + r;
          XT[prow * 128 + (co ^ ((prow & 15) << 3))] = f2bf(acc[pxt][r] + shv[cot8]);
        }
      }
    }
    __syncthreads();
    // flush: thread t writes 64 contiguous channels (128B), linear across block
    {
      u16* dst = (phase == 0) ? qrow : (phase == 1) ? krow : vrow + (phase - 2) * 128;
      #pragma unroll
      for (int c8 = 0; c8 < 8; ++c8)
        *(u16x8*)(dst + c8 * 8) = *(const u16x8*)&XT[pxl * 128 + ((chalf + c8 * 8) ^ swf)];
    }
    __syncthreads();
  }
}

// ---------------- K2: dots partials (split-K over pq) ----------------
__global__ __launch_bounds__(512, 2) void k_dots(
    const u16* __restrict__ QW, const u16* __restrict__ KW, float* __restrict__ Pp)
{
  __shared__ u16 QS[256 * 64];  // [i][k ^ ((i&7)<<3)]
  __shared__ u16 KS[256 * 64];
  const int b = blockIdx.y, ks = blockIdx.x;
  const int nch = (ks == 7) ? 14 : 12;
  const int t = threadIdx.x;
  const int w = t >> 6, l = t & 63, a15 = l & 15, g = l >> 4;
  const int i0w = (w >> 1) * 64, j0w = (w & 1) * 128;

  f32x4 acc[4][8];
  #pragma unroll
  for (int i = 0; i < 4; ++i)
    #pragma unroll
    for (int j = 0; j < 8; ++j) { acc[i][j][0]=0.f; acc[i][j][1]=0.f; acc[i][j][2]=0.f; acc[i][j][3]=0.f; }

  const int srow = t >> 1;
  const int sgr0 = (t & 1) * 4;
  const size_t kb = (size_t)ks * 768 + (size_t)((t & 1) * 32);
  const u16* qsrc = QW + ((size_t)b * 256 + srow) * 6272 + kb;
  const u16* ksrc = KW + ((size_t)b * 256 + srow) * 6272 + kb;
  u16* qdst = &QS[srow * 64];
  u16* kdst = &KS[srow * 64];
  const int swr = srow & 7;

  for (int ch = 0; ch < nch; ++ch) {
    const int k0 = ch * 64;
    #pragma unroll
    for (int gi = 0; gi < 4; ++gi) {
      const int off = ((sgr0 + gi) ^ swr) << 3;
      *(u16x8*)(qdst + off) = *(const u16x8*)(qsrc + k0 + gi * 8);
      *(u16x8*)(kdst + off) = *(const u16x8*)(ksrc + k0 + gi * 8);
    }
    __syncthreads();
    #pragma unroll
    for (int kk = 0; kk < 2; ++kk) {
      s16x8 af[4], bfr[8];
      #pragma unroll
      for (int i4 = 0; i4 < 4; ++i4) {
        const int ir = i0w + i4 * 16 + a15;
        af[i4] = *(const s16x8*)&QS[ir * 64 + (((kk * 4 + g) ^ (ir & 7)) << 3)];
      }
      #pragma unroll
      for (int j8 = 0; j8 < 8; ++j8) {
        const int jr = j0w + j8 * 16 + a15;
        bfr[j8] = *(const s16x8*)&KS[jr * 64 + (((kk * 4 + g) ^ (jr & 7)) << 3)];
      }
      #pragma unroll
      for (int i4 = 0; i4 < 4; ++i4)
        #pragma unroll
        for (int j8 = 0; j8 < 8; ++j8)
          acc[i4][j8] = mfma_bf16(af[i4], bfr[j8], acc[i4][j8]);
    }
    __syncthreads();
  }

  float* pp = Pp + ((size_t)ks * 32 + b) * 256 * 256;
  #pragma unroll
  for (int i4 = 0; i4 < 4; ++i4)
    #pragma unroll
    for (int r = 0; r < 4; ++r) {
      const int ir = i0w + i4 * 16 + g * 4 + r;
      #pragma unroll
      for (int j8 = 0; j8 < 8; ++j8)
        pp[(size_t)ir * 256 + j0w + j8 * 16 + a15] = acc[i4][j8][r];
    }
}

// ---------------- K3: reduce partials + softmax -> P bf16 ----------------
__global__ __launch_bounds__(256, 4) void k_smax(const float* __restrict__ Pp, u16* __restrict__ P)
{
  const int b = blockIdx.y, it = blockIdx.x;
  const int t = threadIdx.x;
  const int row = it * 32 + (t >> 3);
  const int cg = t & 7;
  const size_t rb = ((size_t)b * 256 + row) * 256 + cg * 32;

  f32x4 s[8];
  #pragma unroll
  for (int cc = 0; cc < 8; ++cc) { s[cc][0]=0.f; s[cc][1]=0.f; s[cc][2]=0.f; s[cc][3]=0.f; }
  #pragma unroll 1
  for (int ks = 0; ks < 8; ++ks) {
    const float* src = Pp + (size_t)ks * 32 * 256 * 256 + rb;
    #pragma unroll
    for (int cc = 0; cc < 8; ++cc)
      s[cc] += *(const f32x4*)(src + cc * 4);
  }
  float m = -1e30f;
  #pragma unroll
  for (int cc = 0; cc < 8; ++cc)
    m = fmaxf(m, fmaxf(fmaxf(s[cc][0], s[cc][1]), fmaxf(s[cc][2], s[cc][3])));
  m = fmaxf(m, __shfl_xor(m, 1));
  m = fmaxf(m, __shfl_xor(m, 2));
  m = fmaxf(m, __shfl_xor(m, 4));
  const float CEXP = 0.18033688f;  // 0.125*log2(e)
  float sum = 0.f;
  #pragma unroll
  for (int cc = 0; cc < 8; ++cc)
    #pragma unroll
    for (int e = 0; e < 4; ++e) {
      const float p = exp2f((s[cc][e] - m) * CEXP);
      s[cc][e] = p;
      sum += p;
    }
  sum += __shfl_xor(sum, 1);
  sum += __shfl_xor(sum, 2);
  sum += __shfl_xor(sum, 4);
  const float inv = 1.0f / sum;
  u16* dst = P + rb;
  #pragma unroll
  for (int cc = 0; cc < 8; cc += 2) {
    u16x8 o;
    o[0] = f2bf(s[cc][0] * inv);     o[1] = f2bf(s[cc][1] * inv);
    o[2] = f2bf(s[cc][2] * inv);     o[3] = f2bf(s[cc][3] * inv);
    o[4] = f2bf(s[cc + 1][0] * inv); o[5] = f2bf(s[cc + 1][1] * inv);
    o[6] = f2bf(s[cc + 1][2] * inv); o[7] = f2bf(s[cc + 1][3] * inv);
    *(u16x8*)(dst + cc * 4) = o;
  }
}

// ---------------- K4: PV + gelu -> GN ----------------
__global__ __launch_bounds__(512, 2) void k_pv(
    const u16* __restrict__ P, const u16* __restrict__ VW, u16* __restrict__ GN)
{
  __shared__ u16 VT[256 * 64];  // [m][j ^ ((m&7)<<3)]
  __shared__ u16 PS[256 * 64];  // [i][j ^ ((i&7)<<3)]
  const int b = blockIdx.y, pq = blockIdx.x;
  const int t = threadIdx.x;
  const int w = t >> 6, l = t & 63, a15 = l & 15, g = l >> 4;
  const int m0w = (w >> 1) * 64, i0w = (w & 1) * 128;

  f32x4 acc[4][8];  // [mf][if]
  #pragma unroll
  for (int i = 0; i < 4; ++i)
    #pragma unroll
    for (int j = 0; j < 8; ++j) { acc[i][j][0]=0.f; acc[i][j][1]=0.f; acc[i][j][2]=0.f; acc[i][j][3]=0.f; }

  const int sj0 = (t & 7) * 8;
  const int sm0 = (t >> 3) * 4;
  const u16* vbase = VW + ((size_t)b * 256 + sj0) * 12544 + pq * 256 + sm0;
  const int prow = t >> 1;
  const int pgr0 = (t & 1) * 4;
  const u16* pbase = P + ((size_t)b * 256 + prow) * 256 + (t & 1) * 32;
  u16* psdst = &PS[prow * 64];
  const int pswr = prow & 7;

  for (int jc = 0; jc < 4; ++jc) {
    const int j0 = jc * 64;
    u16x4 rr[8];
    #pragma unroll
    for (int ji = 0; ji < 8; ++ji)
      rr[ji] = *(const u16x4*)(vbase + (size_t)(j0 + ji) * 12544);
    #pragma unroll
    for (int mi = 0; mi < 4; ++mi) {
      u16x8 wv;
      #pragma unroll
      for (int ji = 0; ji < 8; ++ji) wv[ji] = rr[ji][mi];
      const int m = sm0 + mi;
      *(u16x8*)&VT[m * 64 + (((sj0 >> 3) ^ (m & 7)) << 3)] = wv;
    }
    #pragma unroll
    for (int gi = 0; gi < 4; ++gi) {
      const int off = ((pgr0 + gi) ^ pswr) << 3;
      *(u16x8*)(psdst + off) = *(const u16x8*)(pbase + j0 + gi * 8);
    }
    __syncthreads();
    #pragma unroll
    for (int kk = 0; kk < 2; ++kk) {
      s16x8 av[4], bp[8];
      #pragma unroll
      for (int mf = 0; mf < 4; ++mf) {
        const int m = m0w + mf * 16 + a15;
        av[mf] = *(const s16x8*)&VT[m * 64 + (((kk * 4 + g) ^ (m & 7)) << 3)];
      }
      #pragma unroll
      for (int f = 0; f < 8; ++f) {
        const int i = i0w + f * 16 + a15;
        bp[f] = *(const s16x8*)&PS[i * 64 + (((kk * 4 + g) ^ (i & 7)) << 3)];
      }
      #pragma unroll
      for (int mf = 0; mf < 4; ++mf)
        #pragma unroll
        for (int f = 0; f < 8; ++f)
          acc[mf][f] = mfma_bf16(av[mf], bp[f], acc[mf][f]);
    }
    __syncthreads();
  }

  const int pp_ = pq / 7, qq = pq - 7 * pp_;
  #pragma unroll
  for (int f = 0; f < 8; ++f) {
    const int i = i0w + f * 16 + a15;
    const int h1 = i >> 4, w1 = i & 15;
    const size_t gb = ((size_t)b * 12544 + (size_t)((h1 * 7 + pp_) * 112 + w1 * 7 + qq)) * 256;
    #pragma unroll
    for (int mf = 0; mf < 4; ++mf) {
      u16x4 st;
      #pragma unroll
      for (int r = 0; r < 4; ++r) st[r] = f2bf(gelu_f(acc[mf][f][r]));
      *(u16x4*)&GN[gb + m0w + mf * 16 + g * 4] = st;
    }
  }
}

// ---------------- K5: out conv + BN + residual + gelu ----------------
__global__ __launch_bounds__(512, 2) void k_out(
    const u16* __restrict__ GN, const float* __restrict__ wo,
    const float* __restrict__ x, const float* __restrict__ sco,
    const float* __restrict__ sho, float* __restrict__ out)
{
  __shared__ u16 WO[128 * 256];  // [o][k ^ ((o&7)<<3)] bf16, scale-folded
  __shared__ u16 OT[128 * 264];  // [o][px]
  const int b = blockIdx.y;
  const int px0 = blockIdx.x * 256;
  const int t = threadIdx.x;
  const int w = t >> 6, l = t & 63, a15 = l & 15, g = l >> 4;

  {
    const int o = t >> 2, gr0 = (t & 3) * 8;
    const float s = sco[o];
    const float* src = wo + o * 256 + gr0 * 8;
    u16* dr = &WO[o * 256];
    #pragma unroll
    for (int gi = 0; gi < 8; ++gi) {
      const float4 v0 = *(const float4*)(src + gi * 8);
      const float4 v1 = *(const float4*)(src + gi * 8 + 4);
      u16x8 pk;
      pk[0] = f2bf(v0.x * s); pk[1] = f2bf(v0.y * s);
      pk[2] = f2bf(v0.z * s); pk[3] = f2bf(v0.w * s);
      pk[4] = f2bf(v1.x * s); pk[5] = f2bf(v1.y * s);
      pk[6] = f2bf(v1.z * s); pk[7] = f2bf(v1.w * s);
      *(u16x8*)(dr + (((gr0 + gi) ^ (o & 7)) << 3)) = pk;
    }
  }
  __syncthreads();

  const int pw = w >> 1, ow = w & 1;
  const int o0w = ow * 64;
  f32x4 acc[4][4];
  #pragma unroll
  for (int i = 0; i < 4; ++i)
    #pragma unroll
    for (int j = 0; j < 4; ++j) { acc[i][j][0]=0.f; acc[i][j][1]=0.f; acc[i][j][2]=0.f; acc[i][j][3]=0.f; }

  #pragma unroll 1
  for (int ksl = 0; ksl < 8; ++ksl) {
    s16x8 af[4], bw[4];
    #pragma unroll
    for (int pxf = 0; pxf < 4; ++pxf) {
      const int row = px0 + pw * 64 + pxf * 16 + a15;
      af[pxf] = ld8(GN + ((size_t)b * 12544 + row) * 256 + ksl * 32 + g * 8);
    }
    #pragma unroll
    for (int of = 0; of < 4; ++of) {
      const int o = o0w + of * 16 + a15;
      bw[of] = *(const s16x8*)&WO[o * 256 + (((ksl * 4 + g) ^ (o & 7)) << 3)];
    }
    #pragma unroll
    for (int pxf = 0; pxf < 4; ++pxf)
      #pragma unroll
      for (int of = 0; of < 4; ++of)
        acc[pxf][of] = mfma_bf16(af[pxf], bw[of], acc[pxf][of]);
  }

  #pragma unroll
  for (int pxf = 0; pxf < 4; ++pxf)
    #pragma unroll
    for (int of = 0; of < 4; ++of) {
      u16x4 st;
      #pragma unroll
      for (int r = 0; r < 4; ++r) st[r] = f2bf(acc[pxf][of][r]);
      *(u16x4*)&OT[(o0w + of * 16 + a15) * 264 + pw * 64 + pxf * 16 + g * 4] = st;
    }
  __syncthreads();

  const int o2 = t >> 2;
  const float sh = sho[o2];
  const size_t xb = ((size_t)b * 128 + o2) * 12544 + px0;
  #pragma unroll 2
  for (int ii = 0; ii < 16; ++ii) {
    const int po = ii * 16 + (t & 3) * 4;
    const u16x4 zt = *(const u16x4*)&OT[o2 * 264 + po];
    const float4 xv = *(const float4*)(x + xb + po);
    float4 r;
    r.x = gelu_f(bf2f(zt[0]) + sh + xv.x);
    r.y = gelu_f(bf2f(zt[1]) + sh + xv.y);
    r.z = gelu_f(bf2f(zt[2]) + sh + xv.z);
    r.w = gelu_f(bf2f(zt[3]) + sh + xv.w);
    *(float4*)(out + xb + po) = r;
  }
}

extern "C" void kernel_launch(void* const* d_in, const int* in_sizes, int n_in,
                              void* d_out, int out_size, void* d_ws, size_t ws_size,
                              hipStream_t stream) {
  (void)in_sizes; (void)n_in; (void)out_size; (void)ws_size;
  const float* x   = (const float*)d_in[0];
  const float* wq  = (const float*)d_in[1];
  const float* gq  = (const float*)d_in[2];
  const float* bq  = (const float*)d_in[3];
  const float* mq  = (const float*)d_in[4];
  const float* vq  = (const float*)d_in[5];
  const float* wk  = (const float*)d_in[6];
  const float* gk  = (const float*)d_in[7];
  const float* bk  = (const float*)d_in[8];
  const float* mk  = (const float*)d_in[9];
  const float* vk  = (const float*)d_in[10];
  const float* wv  = (const float*)d_in[11];
  const float* gv  = (const float*)d_in[12];
  const float* bv  = (const float*)d_in[13];
  const float* mv  = (const float*)d_in[14];
  const float* vv  = (const float*)d_in[15];
  const float* wo  = (const float*)d_in[16];
  const float* bo  = (const float*)d_in[17];
  const float* go  = (const float*)d_in[18];
  const float* bbo = (const float*)d_in[19];
  const float* mo  = (const float*)d_in[20];
  const float* vo  = (const float*)d_in[21];

  u16* QW = (u16*)d_ws;                 // 51,380,224 elems
  u16* KW = QW + 51380224u;
  u16* VW = KW + 51380224u;             // 102,760,448 elems
  u16* GN = VW + 102760448u;            // 102,760,448 elems
  u16* P  = QW;                          // alias (live after k_dots)
  float* Pp = (float*)GN;                // alias 67MB (live k_dots..k_smax)
  u16* wfused = GN;                      // alias 128KB (live k_wconv..k_qkv)
  u16* XN = GN + 1048576u;               // alias 102.7MB at +2MB (live k_xpose..k_qkv)
  float* sc512 = (float*)(GN + 102760448u);
  float* sh512 = sc512 + 512;
  float* sco = sh512 + 512;
  float* sho = sco + 128;

  k_params<<<1, 512, 0, stream>>>(gq, bq, mq, vq, gk, bk, mk, vk, gv, bv, mv, vv,
                                  bo, go, bbo, mo, vo, sc512, sh512, sco, sho);
  k_wconv<<<64, 256, 0, stream>>>(wq, wk, wv, sc512, wfused);
  k_xpose<<<dim3(49, 32), 512, 0, stream>>>(x, XN);
  k_qkv<<<dim3(98, 32), 256, 0, stream>>>(XN, wfused, sh512, QW, KW, VW);
  k_dots<<<dim3(8, 32), 512, 0, stream>>>(QW, KW, Pp);
  k_smax<<<dim3(8, 32), 256, 0, stream>>>(Pp, P);
  k_pv<<<dim3(49, 32), 512, 0, stream>>>(P, VW, GN);
  k_out<<<dim3(49, 32), 512, 0, stream>>>(GN, wo, x, sco, sho, (float*)d_out);
}

// Round 9
// 729.867 us; speedup vs baseline: 1.1787x; 1.1787x over previous
//
#include <hip/hip_runtime.h>

// Windowed attention block (B=32, C=128->256->128, H=W=112, WS=7, T=256 windows).
// fp32 I/O, bf16 MFMA internal, fp16 dots-partials.
// ws (616.6MB): QW [32][256 j][49 pq][128 c] bf16 | KW same | VW [32][256 j][49 pq *256 d] bf16
//               GN [32][12544 px][256 d] bf16 | params f32
// aliases: P bf16 [32][256][256] (slot-permuted j) -> QW base (after k_dots reads QW)
//          Pp16 half [8][32][256][256 slots] -> GN base (live k_dots..k_smax)
//          wfused bf16 [512][128] -> GN base (live k_wconv..k_qkv)
// Slot permutation (within each 128-j half): slot s holds true j =
//   (s&128) + ((s>>5)&3)*32 + (s&1)*16 + ((s>>1)&15).  k_pv's V-gather applies it.

typedef unsigned short u16;
typedef unsigned int u32;
typedef short s16x8 __attribute__((ext_vector_type(8)));
typedef float f32x4 __attribute__((ext_vector_type(4)));
typedef u16 u16x8 __attribute__((ext_vector_type(8)));
typedef u16 u16x4 __attribute__((ext_vector_type(4)));

#define EPSV 1e-5f

__device__ __forceinline__ float bf2f(u16 h) {
  u32 u = ((u32)h) << 16;
  return __builtin_bit_cast(float, u);
}
__device__ __forceinline__ u16 f2bf(float f) {
  u32 u = __builtin_bit_cast(u32, f);
  u += 0x7FFFu + ((u >> 16) & 1u);
  return (u16)(u >> 16);
}
__device__ __forceinline__ u32 pk_half2(float a, float b) {
  const u16 lo = __builtin_bit_cast(u16, (_Float16)a);
  const u16 hi = __builtin_bit_cast(u16, (_Float16)b);
  return (u32)lo | ((u32)hi << 16);
}
__device__ __forceinline__ float h2f(u16 h) {
  return (float)__builtin_bit_cast(_Float16, h);
}
__device__ __forceinline__ s16x8 ld8(const u16* p) { return *(const s16x8*)p; }
__device__ __forceinline__ f32x4 mfma_bf16(s16x8 a, s16x8 b, f32x4 c) {
  return __builtin_amdgcn_mfma_f32_16x16x32_bf16(a, b, c, 0, 0, 0);
}
__device__ __forceinline__ float gelu_f(float v) {
  float e = exp2f(-2.3022083f * (v + 0.044715f * v * v * v));
  return v / (1.0f + e);
}

// ---------------- K0: fold BN params ----------------
__global__ void k_params(
    const float* __restrict__ gq, const float* __restrict__ bq, const float* __restrict__ mq, const float* __restrict__ vq,
    const float* __restrict__ gk, const float* __restrict__ bk, const float* __restrict__ mk, const float* __restrict__ vk,
    const float* __restrict__ gv, const float* __restrict__ bv, const float* __restrict__ mv, const float* __restrict__ vv,
    const float* __restrict__ bo, const float* __restrict__ go, const float* __restrict__ bbo, const float* __restrict__ mo,
    const float* __restrict__ vo,
    float* __restrict__ sc512, float* __restrict__ sh512, float* __restrict__ sco, float* __restrict__ sho)
{
  const int i = threadIdx.x;
  if (i < 128) {
    const float s = gq[i] * rsqrtf(vq[i] + EPSV);
    sc512[i] = s;
    sh512[i] = bq[i] - mq[i] * s;
    const float so = go[i] * rsqrtf(vo[i] + EPSV);
    sco[i] = so;
    sho[i] = (bo[i] - mo[i]) * so + bbo[i];
  } else if (i < 256) {
    const int c = i - 128;
    const float s = gk[c] * rsqrtf(vk[c] + EPSV);
    sc512[i] = s;
    sh512[i] = bk[c] - mk[c] * s;
  } else if (i < 512) {
    const int c = i - 256;
    const float s = gv[c] * rsqrtf(vv[c] + EPSV);
    sc512[i] = s;
    sh512[i] = bv[c] - mv[c] * s;
  }
}

// ---------------- K0b: convert+scale-fold QKV weights to bf16 ----------------
__global__ void k_wconv(const float* __restrict__ wq, const float* __restrict__ wk,
                        const float* __restrict__ wv, const float* __restrict__ sc512,
                        u16* __restrict__ wfused)
{
  const int idx4 = (blockIdx.x * 256 + threadIdx.x) * 4;  // 0..65532
  const int co = idx4 >> 7, c = idx4 & 127;
  const float* src = (co < 128) ? (wq + co * 128 + c)
                   : (co < 256) ? (wk + (co - 128) * 128 + c)
                                : (wv + (co - 256) * 128 + c);
  const float s = sc512[co];
  const float4 v = *(const float4*)src;
  u16x4 r;
  r[0] = f2bf(v.x * s); r[1] = f2bf(v.y * s);
  r[2] = f2bf(v.z * s); r[3] = f2bf(v.w * s);
  *(u16x4*)(wfused + idx4) = r;
}

// ---------------- K1: QKV projection (+folded BN) ----------------
// Round-4 structure (empirically fastest): px-tile 256, 256 thr, x staged via LDS,
// dbuf weights, 4 phases of 128 co -> LDS out-tile -> full-row flush.
__global__ __launch_bounds__(256, 2) void k_qkv(
    const float* __restrict__ x, const u16* __restrict__ wfused,
    const float* __restrict__ sh512,
    u16* __restrict__ QW, u16* __restrict__ KW, u16* __restrict__ VW)
{
  __shared__ u16 XT[256 * 128];  // stage x [px][c ^ ((px&15)<<3)]; reused as out tile
  const int b = blockIdx.y;
  const int px0 = blockIdx.x * 256;
  const int t = threadIdx.x;

  // stage x tile (NCHW fp32 -> LDS bf16 transposed, XOR-swizzled)
  {
    const float* xp = x + (size_t)b * 128u * 12544u + (size_t)(px0 + t);
    const int sw = (t & 15) << 3;
    #pragma unroll 8
    for (int c = 0; c < 128; c += 4) {
      u16x4 pk;
      pk[0] = f2bf(xp[(size_t)(c + 0) * 12544u]);
      pk[1] = f2bf(xp[(size_t)(c + 1) * 12544u]);
      pk[2] = f2bf(xp[(size_t)(c + 2) * 12544u]);
      pk[3] = f2bf(xp[(size_t)(c + 3) * 12544u]);
      *(u16x4*)&XT[t * 128 + (c ^ sw)] = pk;
    }
  }
  __syncthreads();

  const int w = t >> 6, l = t & 63, a15 = l & 15, g = l >> 4;

  // A fragments into registers; XT dead afterwards
  s16x8 af[4][4];
  #pragma unroll
  for (int pxt = 0; pxt < 4; ++pxt) {
    const int row = w * 64 + pxt * 16 + a15;
    const int sw = (row & 15) << 3;
    #pragma unroll
    for (int ks = 0; ks < 4; ++ks) {
      const int cc = ks * 32 + g * 8;
      af[pxt][ks] = *(const s16x8*)&XT[row * 128 + (cc ^ sw)];
    }
  }
  __syncthreads();

  // per-thread output row (thread t owns pixel px0+t)
  const int px = px0 + t;
  const int hh = px / 112, ww = px - hh * 112;
  const int h1 = hh / 7, p = hh - h1 * 7;
  const int w1 = ww / 7, q = ww - w1 * 7;
  const int j = h1 * 16 + w1, pq = p * 7 + q;
  u16* const qrow = QW + ((size_t)(b * 256 + j) * 49 + pq) * 128;
  u16* const krow = KW + ((size_t)(b * 256 + j) * 49 + pq) * 128;
  u16* const vrow = VW + (size_t)(b * 256 + j) * 12544 + pq * 256;

  #pragma unroll 1
  for (int phase = 0; phase < 4; ++phase) {
    // double-buffered weight fragments over cot8
    s16x8 bcur[4];
    {
      const u16* wrow = wfused + (u32)(phase * 128 + a15) * 128u;
      #pragma unroll
      for (int ks = 0; ks < 4; ++ks) bcur[ks] = ld8(wrow + ks * 32 + g * 8);
    }
    #pragma unroll 1
    for (int cot8 = 0; cot8 < 8; ++cot8) {
      s16x8 bnext[4];
      if (cot8 < 7) {
        const u16* wrow = wfused + (u32)(phase * 128 + (cot8 + 1) * 16 + a15) * 128u;
        #pragma unroll
        for (int ks = 0; ks < 4; ++ks) bnext[ks] = ld8(wrow + ks * 32 + g * 8);
      }
      f32x4 acc[4];
      #pragma unroll
      for (int pxt = 0; pxt < 4; ++pxt) { acc[pxt][0]=0.f; acc[pxt][1]=0.f; acc[pxt][2]=0.f; acc[pxt][3]=0.f; }
      #pragma unroll
      for (int ks = 0; ks < 4; ++ks)
        #pragma unroll
        for (int pxt = 0; pxt < 4; ++pxt)
          acc[pxt] = mfma_bf16(af[pxt][ks], bcur[ks], acc[pxt]);

      const float sh = sh512[phase * 128 + cot8 * 16 + a15];
      const int co = cot8 * 16 + a15;  // within-phase channel
      #pragma unroll
      for (int pxt = 0; pxt < 4; ++pxt) {
        #pragma unroll
        for (int r = 0; r < 4; ++r) {
          const int pxl = w * 64 + pxt * 16 + g * 4 + r;
          XT[pxl * 128 + (co ^ ((pxl & 15) << 3))] = f2bf(acc[pxt][r] + sh);
        }
      }
      #pragma unroll
      for (int ks = 0; ks < 4; ++ks) bcur[ks] = bnext[ks];
    }
    __syncthreads();
    // flush: thread t writes its full 128-channel row (256B contiguous)
    {
      u16* dst = (phase == 0) ? qrow : (phase == 1) ? krow : vrow + (phase - 2) * 128;
      const int sw = (t & 15) << 3;
      #pragma unroll
      for (int c8 = 0; c8 < 16; ++c8)
        *(u16x8*)(dst + c8 * 8) = *(const u16x8*)&XT[t * 128 + ((c8 * 8) ^ sw)];
    }
    __syncthreads();
  }
}

// ---------------- K2: dots partials (split-K over pq), fp16 slot-permuted out ----------------
__global__ __launch_bounds__(512, 2) void k_dots(
    const u16* __restrict__ QW, const u16* __restrict__ KW, u16* __restrict__ Pp16)
{
  __shared__ u16 QS[256 * 64];  // [i][k ^ ((i&7)<<3)]
  __shared__ u16 KS[256 * 64];
  const int b = blockIdx.y, ks = blockIdx.x;
  const int nch = (ks == 7) ? 14 : 12;
  const int t = threadIdx.x;
  const int w = t >> 6, l = t & 63, a15 = l & 15, g = l >> 4;
  const int i0w = (w >> 1) * 64, j0w = (w & 1) * 128;

  f32x4 acc[4][8];
  #pragma unroll
  for (int i = 0; i < 4; ++i)
    #pragma unroll
    for (int j = 0; j < 8; ++j) { acc[i][j][0]=0.f; acc[i][j][1]=0.f; acc[i][j][2]=0.f; acc[i][j][3]=0.f; }

  const int srow = t >> 1;
  const int sgr0 = (t & 1) * 4;
  const size_t kb = (size_t)ks * 768 + (size_t)((t & 1) * 32);
  const u16* qsrc = QW + ((size_t)b * 256 + srow) * 6272 + kb;
  const u16* ksrc = KW + ((size_t)b * 256 + srow) * 6272 + kb;
  u16* qdst = &QS[srow * 64];
  u16* kdst = &KS[srow * 64];
  const int swr = srow & 7;

  for (int ch = 0; ch < nch; ++ch) {
    const int k0 = ch * 64;
    #pragma unroll
    for (int gi = 0; gi < 4; ++gi) {
      const int off = ((sgr0 + gi) ^ swr) << 3;
      *(u16x8*)(qdst + off) = *(const u16x8*)(qsrc + k0 + gi * 8);
      *(u16x8*)(kdst + off) = *(const u16x8*)(ksrc + k0 + gi * 8);
    }
    __syncthreads();
    #pragma unroll
    for (int kk = 0; kk < 2; ++kk) {
      s16x8 af[4], bfr[8];
      #pragma unroll
      for (int i4 = 0; i4 < 4; ++i4) {
        const int ir = i0w + i4 * 16 + a15;
        af[i4] = *(const s16x8*)&QS[ir * 64 + (((kk * 4 + g) ^ (ir & 7)) << 3)];
      }
      #pragma unroll
      for (int j8 = 0; j8 < 8; ++j8) {
        const int jr = j0w + j8 * 16 + a15;
        bfr[j8] = *(const s16x8*)&KS[jr * 64 + (((kk * 4 + g) ^ (jr & 7)) << 3)];
      }
      #pragma unroll
      for (int i4 = 0; i4 < 4; ++i4)
        #pragma unroll
        for (int j8 = 0; j8 < 8; ++j8)
          acc[i4][j8] = mfma_bf16(af[i4], bfr[j8], acc[i4][j8]);
    }
    __syncthreads();
  }

  // epilogue: pack (j8=2m, 2m+1) pairs as half2 at slot j0w + m*32 + a15*2 (+lo)
  u16* pp = Pp16 + ((size_t)ks * 32 + b) * 65536;
  #pragma unroll
  for (int i4 = 0; i4 < 4; ++i4)
    #pragma unroll
    for (int r = 0; r < 4; ++r) {
      const int ir = i0w + i4 * 16 + g * 4 + r;
      u32* prow32 = (u32*)(pp + (size_t)ir * 256) + (j0w >> 1) + a15;
      #pragma unroll
      for (int m = 0; m < 4; ++m)
        prow32[m * 16] = pk_half2(acc[i4][2 * m][r], acc[i4][2 * m + 1][r]);
    }
}

// ---------------- K3: reduce fp16 partials + softmax -> P bf16 (slot order) ----------------
__global__ __launch_bounds__(256, 4) void k_smax(const u16* __restrict__ Pp16, u16* __restrict__ P)
{
  const int b = blockIdx.y, it = blockIdx.x;
  const int t = threadIdx.x;
  const int row = it * 32 + (t >> 3);
  const int cg = t & 7;
  const size_t rb = ((size_t)b * 256 + row) * 256 + cg * 32;

  float s[32];
  #pragma unroll
  for (int e = 0; e < 32; ++e) s[e] = 0.f;
  #pragma unroll 1
  for (int ks = 0; ks < 8; ++ks) {
    const u16* src = Pp16 + (size_t)ks * 2097152 + rb;  // 32*256*256 per ks
    #pragma unroll
    for (int c8 = 0; c8 < 4; ++c8) {
      const u16x8 v = *(const u16x8*)(src + c8 * 8);
      #pragma unroll
      for (int e = 0; e < 8; ++e)
        s[c8 * 8 + e] += h2f((u16)v[e]);
    }
  }
  float m = -1e30f;
  #pragma unroll
  for (int e = 0; e < 32; ++e) m = fmaxf(m, s[e]);
  m = fmaxf(m, __shfl_xor(m, 1));
  m = fmaxf(m, __shfl_xor(m, 2));
  m = fmaxf(m, __shfl_xor(m, 4));
  const float CEXP = 0.18033688f;  // 0.125*log2(e)
  float sum = 0.f;
  #pragma unroll
  for (int e = 0; e < 32; ++e) {
    const float pvv = exp2f((s[e] - m) * CEXP);
    s[e] = pvv;
    sum += pvv;
  }
  sum += __shfl_xor(sum, 1);
  sum += __shfl_xor(sum, 2);
  sum += __shfl_xor(sum, 4);
  const float inv = 1.0f / sum;
  u16* dst = P + rb;
  #pragma unroll
  for (int c8 = 0; c8 < 4; ++c8) {
    u16x8 o;
    #pragma unroll
    for (int e = 0; e < 8; ++e) o[e] = f2bf(s[c8 * 8 + e] * inv);
    *(u16x8*)(dst + c8 * 8) = o;
  }
}

// ---------------- K4: PV + gelu -> GN (V gathered via slot permutation) ----------------
__global__ __launch_bounds__(512, 2) void k_pv(
    const u16* __restrict__ P, const u16* __restrict__ VW, u16* __restrict__ GN)
{
  __shared__ u16 VT[256 * 64];  // [m][slot ^ ((m&7)<<3)]
  __shared__ u16 PS[256 * 64];  // [i][slot ^ ((i&7)<<3)]
  const int b = blockIdx.y, pq = blockIdx.x;
  const int t = threadIdx.x;
  const int w = t >> 6, l = t & 63, a15 = l & 15, g = l >> 4;
  const int m0w = (w >> 1) * 64, i0w = (w & 1) * 128;

  f32x4 acc[4][8];  // [mf][if]
  #pragma unroll
  for (int i = 0; i < 4; ++i)
    #pragma unroll
    for (int j = 0; j < 8; ++j) { acc[i][j][0]=0.f; acc[i][j][1]=0.f; acc[i][j][2]=0.f; acc[i][j][3]=0.f; }

  const int sj0 = (t & 7) * 8;
  const int sm0 = (t >> 3) * 4;
  const u16* vbase0 = VW + (size_t)b * 3211264 + pq * 256 + sm0;  // no j component
  const int prow = t >> 1;
  const int pgr0 = (t & 1) * 4;
  const u16* pbase = P + ((size_t)b * 256 + prow) * 256 + (t & 1) * 32;
  u16* psdst = &PS[prow * 64];
  const int pswr = prow & 7;

  for (int jc = 0; jc < 4; ++jc) {
    const int j0 = jc * 64;
    u16x4 rr[8];
    #pragma unroll
    for (int ji = 0; ji < 8; ++ji) {
      const int s = j0 + sj0 + ji;
      const int tj = (s & 128) + ((s >> 5) & 3) * 32 + (s & 1) * 16 + ((s >> 1) & 15);
      rr[ji] = *(const u16x4*)(vbase0 + (size_t)tj * 12544);
    }
    #pragma unroll
    for (int mi = 0; mi < 4; ++mi) {
      u16x8 wv;
      #pragma unroll
      for (int ji = 0; ji < 8; ++ji) wv[ji] = rr[ji][mi];
      const int m = sm0 + mi;
      *(u16x8*)&VT[m * 64 + (((sj0 >> 3) ^ (m & 7)) << 3)] = wv;
    }
    #pragma unroll
    for (int gi = 0; gi < 4; ++gi) {
      const int off = ((pgr0 + gi) ^ pswr) << 3;
      *(u16x8*)(psdst + off) = *(const u16x8*)(pbase + j0 + gi * 8);
    }
    __syncthreads();
    #pragma unroll
    for (int kk = 0; kk < 2; ++kk) {
      s16x8 av[4], bp[8];
      #pragma unroll
      for (int mf = 0; mf < 4; ++mf) {
        const int m = m0w + mf * 16 + a15;
        av[mf] = *(const s16x8*)&VT[m * 64 + (((kk * 4 + g) ^ (m & 7)) << 3)];
      }
      #pragma unroll
      for (int f = 0; f < 8; ++f) {
        const int i = i0w + f * 16 + a15;
        bp[f] = *(const s16x8*)&PS[i * 64 + (((kk * 4 + g) ^ (i & 7)) << 3)];
      }
      #pragma unroll
      for (int mf = 0; mf < 4; ++mf)
        #pragma unroll
        for (int f = 0; f < 8; ++f)
          acc[mf][f] = mfma_bf16(av[mf], bp[f], acc[mf][f]);
    }
    __syncthreads();
  }

  const int pp_ = pq / 7, qq = pq - 7 * pp_;
  #pragma unroll
  for (int f = 0; f < 8; ++f) {
    const int i = i0w + f * 16 + a15;
    const int h1 = i >> 4, w1 = i & 15;
    const size_t gb = ((size_t)b * 12544 + (size_t)((h1 * 7 + pp_) * 112 + w1 * 7 + qq)) * 256;
    #pragma unroll
    for (int mf = 0; mf < 4; ++mf) {
      u16x4 st;
      #pragma unroll
      for (int r = 0; r < 4; ++r) st[r] = f2bf(gelu_f(acc[mf][f][r]));
      *(u16x4*)&GN[gb + m0w + mf * 16 + g * 4] = st;
    }
  }
}

// ---------------- K5: out conv + BN + residual + gelu ----------------
__global__ __launch_bounds__(512, 2) void k_out(
    const u16* __restrict__ GN, const float* __restrict__ wo,
    const float* __restrict__ x, const float* __restrict__ sco,
    const float* __restrict__ sho, float* __restrict__ out)
{
  __shared__ u16 WO[128 * 256];  // [o][k ^ ((o&7)<<3)] bf16, scale-folded
  __shared__ u16 OT[128 * 264];  // [o][px]
  const int b = blockIdx.y;
  const int px0 = blockIdx.x * 256;
  const int t = threadIdx.x;
  const int w = t >> 6, l = t & 63, a15 = l & 15, g = l >> 4;

  {
    const int o = t >> 2, gr0 = (t & 3) * 8;
    const float s = sco[o];
    const float* src = wo + o * 256 + gr0 * 8;
    u16* dr = &WO[o * 256];
    #pragma unroll
    for (int gi = 0; gi < 8; ++gi) {
      const float4 v0 = *(const float4*)(src + gi * 8);
      const float4 v1 = *(const float4*)(src + gi * 8 + 4);
      u16x8 pk;
      pk[0] = f2bf(v0.x * s); pk[1] = f2bf(v0.y * s);
      pk[2] = f2bf(v0.z * s); pk[3] = f2bf(v0.w * s);
      pk[4] = f2bf(v1.x * s); pk[5] = f2bf(v1.y * s);
      pk[6] = f2bf(v1.z * s); pk[7] = f2bf(v1.w * s);
      *(u16x8*)(dr + (((gr0 + gi) ^ (o & 7)) << 3)) = pk;
    }
  }
  __syncthreads();

  const int pw = w >> 1, ow = w & 1;
  const int o0w = ow * 64;
  f32x4 acc[4][4];
  #pragma unroll
  for (int i = 0; i < 4; ++i)
    #pragma unroll
    for (int j = 0; j < 4; ++j) { acc[i][j][0]=0.f; acc[i][j][1]=0.f; acc[i][j][2]=0.f; acc[i][j][3]=0.f; }

  #pragma unroll 1
  for (int ksl = 0; ksl < 8; ++ksl) {
    s16x8 af[4], bw[4];
    #pragma unroll
    for (int pxf = 0; pxf < 4; ++pxf) {
      const int row = px0 + pw * 64 + pxf * 16 + a15;
      af[pxf] = ld8(GN + ((size_t)b * 12544 + row) * 256 + ksl * 32 + g * 8);
    }
    #pragma unroll
    for (int of = 0; of < 4; ++of) {
      const int o = o0w + of * 16 + a15;
      bw[of] = *(const s16x8*)&WO[o * 256 + (((ksl * 4 + g) ^ (o & 7)) << 3)];
    }
    #pragma unroll
    for (int pxf = 0; pxf < 4; ++pxf)
      #pragma unroll
      for (int of = 0; of < 4; ++of)
        acc[pxf][of] = mfma_bf16(af[pxf], bw[of], acc[pxf][of]);
  }

  #pragma unroll
  for (int pxf = 0; pxf < 4; ++pxf)
    #pragma unroll
    for (int of = 0; of < 4; ++of) {
      u16x4 st;
      #pragma unroll
      for (int r = 0; r < 4; ++r) st[r] = f2bf(acc[pxf][of][r]);
      *(u16x4*)&OT[(o0w + of * 16 + a15) * 264 + pw * 64 + pxf * 16 + g * 4] = st;
    }
  __syncthreads();

  const int o2 = t >> 2;
  const float sh = sho[o2];
  const size_t xb = ((size_t)b * 128 + o2) * 12544 + px0;
  #pragma unroll 2
  for (int ii = 0; ii < 16; ++ii) {
    const int po = ii * 16 + (t & 3) * 4;
    const u16x4 zt = *(const u16x4*)&OT[o2 * 264 + po];
    const float4 xv = *(const float4*)(x + xb + po);
    float4 r;
    r.x = gelu_f(bf2f(zt[0]) + sh + xv.x);
    r.y = gelu_f(bf2f(zt[1]) + sh + xv.y);
    r.z = gelu_f(bf2f(zt[2]) + sh + xv.z);
    r.w = gelu_f(bf2f(zt[3]) + sh + xv.w);
    *(float4*)(out + xb + po) = r;
  }
}

extern "C" void kernel_launch(void* const* d_in, const int* in_sizes, int n_in,
                              void* d_out, int out_size, void* d_ws, size_t ws_size,
                              hipStream_t stream) {
  (void)in_sizes; (void)n_in; (void)out_size; (void)ws_size;
  const float* x   = (const float*)d_in[0];
  const float* wq  = (const float*)d_in[1];
  const float* gq  = (const float*)d_in[2];
  const float* bq  = (const float*)d_in[3];
  const float* mq  = (const float*)d_in[4];
  const float* vq  = (const float*)d_in[5];
  const float* wk  = (const float*)d_in[6];
  const float* gk  = (const float*)d_in[7];
  const float* bk  = (const float*)d_in[8];
  const float* mk  = (const float*)d_in[9];
  const float* vk  = (const float*)d_in[10];
  const float* wv  = (const float*)d_in[11];
  const float* gv  = (const float*)d_in[12];
  const float* bv  = (const float*)d_in[13];
  const float* mv  = (const float*)d_in[14];
  const float* vv  = (const float*)d_in[15];
  const float* wo  = (const float*)d_in[16];
  const float* bo  = (const float*)d_in[17];
  const float* go  = (const float*)d_in[18];
  const float* bbo = (const float*)d_in[19];
  const float* mo  = (const float*)d_in[20];
  const float* vo  = (const float*)d_in[21];

  u16* QW = (u16*)d_ws;                 // 51,380,224 elems
  u16* KW = QW + 51380224u;
  u16* VW = KW + 51380224u;             // 102,760,448 elems
  u16* GN = VW + 102760448u;            // 102,760,448 elems
  u16* P  = QW;                          // alias (live after k_dots)
  u16* Pp16 = GN;                        // alias 134MB fp16 (live k_dots..k_smax)
  u16* wfused = GN;                      // alias 128KB (live k_wconv..k_qkv; dead before k_dots)
  float* sc512 = (float*)(GN + 102760448u);
  float* sh512 = sc512 + 512;
  float* sco = sh512 + 512;
  float* sho = sco + 128;

  k_params<<<1, 512, 0, stream>>>(gq, bq, mq, vq, gk, bk, mk, vk, gv, bv, mv, vv,
                                  bo, go, bbo, mo, vo, sc512, sh512, sco, sho);
  k_wconv<<<64, 256, 0, stream>>>(wq, wk, wv, sc512, wfused);
  k_qkv<<<dim3(49, 32), 256, 0, stream>>>(x, wfused, sh512, QW, KW, VW);
  k_dots<<<dim3(8, 32), 512, 0, stream>>>(QW, KW, Pp16);
  k_smax<<<dim3(8, 32), 256, 0, stream>>>(Pp16, P);
  k_pv<<<dim3(49, 32), 512, 0, stream>>>(P, VW, GN);
  k_out<<<dim3(49, 32), 512, 0, stream>>>(GN, wo, x, sco, sho, (float*)d_out);
}